// Round 1
// baseline (651.999 us; speedup 1.0000x reference)
//
#include <hip/hip_runtime.h>
#include <cstdint>
#include <math.h>

#define G 64
#define S 32
#define G3 (G*G*G)
#define S3 (S*S*S)

// ---------------------------------------------------------------- helpers

__device__ __forceinline__ float sigmoidf_(float v) {
    return 1.0f / (1.0f + expf(-v));
}

// ---------------------------------------------------------------- parent occupancy
__global__ __launch_bounds__(256) void k_pocc(const float* __restrict__ x,
                                              unsigned char* __restrict__ pocc) {
    int p = blockIdx.x * 256 + threadIdx.x;
    if (p >= S3) return;
    int pz = p & 31, py = (p >> 5) & 31, px = p >> 10;
    const float* b = x + (((size_t)(px * 2) * G + py * 2) * G + pz * 2);
    bool occ = false;
    #pragma unroll
    for (int a = 0; a < 2; a++)
        #pragma unroll
        for (int bb = 0; bb < 2; bb++)
            #pragma unroll
            for (int c = 0; c < 2; c++)
                occ = occ || (b[((size_t)a * G + bb) * G + c] > 0.0f);
    pocc[p] = occ ? 1 : 0;
}

// ---------------------------------------------------------------- FEL conv1: 1->16, 3^3, relu, mask by pf
__global__ __launch_bounds__(256) void k_fel1(const unsigned char* __restrict__ pocc,
                                              const float* __restrict__ w1,
                                              const float* __restrict__ b1,
                                              float* __restrict__ h1) {
    int p = blockIdx.x * 256 + threadIdx.x;
    if (p >= S3) return;
    int pz = p & 31, py = (p >> 5) & 31, px = p >> 10;
    float* o = h1 + (size_t)p * 16;
    if (!pocc[p]) {
        #pragma unroll
        for (int i = 0; i < 16; i++) o[i] = 0.0f;
        return;
    }
    float acc[16];
    #pragma unroll
    for (int i = 0; i < 16; i++) acc[i] = b1[i];
    for (int dx = -1; dx <= 1; ++dx) {
        int nx = px + dx; if ((unsigned)nx >= S) continue;
        for (int dy = -1; dy <= 1; ++dy) {
            int ny = py + dy; if ((unsigned)ny >= S) continue;
            for (int dz = -1; dz <= 1; ++dz) {
                int nz = pz + dz; if ((unsigned)nz >= S) continue;
                if (pocc[(nx * S + ny) * S + nz]) {
                    const float* w = w1 + (((dx + 1) * 3 + (dy + 1)) * 3 + (dz + 1)) * 16;
                    #pragma unroll
                    for (int i = 0; i < 16; i++) acc[i] += w[i];
                }
            }
        }
    }
    #pragma unroll
    for (int i = 0; i < 16; i++) o[i] = fmaxf(acc[i], 0.0f);
}

// ---------------------------------------------------------------- FEL conv2: 16->16, 3^3, no relu, mask by pf
__global__ __launch_bounds__(256) void k_fel2(const unsigned char* __restrict__ pocc,
                                              const float* __restrict__ h1,
                                              const float* __restrict__ w2,
                                              const float* __restrict__ b2,
                                              float* __restrict__ h2) {
    int p = blockIdx.x * 256 + threadIdx.x;
    if (p >= S3) return;
    int pz = p & 31, py = (p >> 5) & 31, px = p >> 10;
    float* o = h2 + (size_t)p * 16;
    if (!pocc[p]) {
        #pragma unroll
        for (int i = 0; i < 16; i++) o[i] = 0.0f;
        return;
    }
    float acc[16];
    #pragma unroll
    for (int i = 0; i < 16; i++) acc[i] = b2[i];
    for (int dx = -1; dx <= 1; ++dx) {
        int nx = px + dx; if ((unsigned)nx >= S) continue;
        for (int dy = -1; dy <= 1; ++dy) {
            int ny = py + dy; if ((unsigned)ny >= S) continue;
            for (int dz = -1; dz <= 1; ++dz) {
                int nz = pz + dz; if ((unsigned)nz >= S) continue;
                const float* f = h1 + (size_t)((nx * S + ny) * S + nz) * 16;
                const float* w = w2 + (((dx + 1) * 3 + (dy + 1)) * 3 + (dz + 1)) * 256;
                #pragma unroll
                for (int ci = 0; ci < 16; ++ci) {
                    float fv = f[ci];
                    #pragma unroll
                    for (int co = 0; co < 16; ++co)
                        acc[co] = fmaf(fv, w[ci * 16 + co], acc[co]);
                }
            }
        }
    }
    #pragma unroll
    for (int i = 0; i < 16; i++) o[i] = acc[i];
}

// ---------------------------------------------------------------- generative up (k2 s2 transposed conv) -> prob_f on child grid
__global__ __launch_bounds__(256) void k_up(const unsigned char* __restrict__ pocc,
                                            const float* __restrict__ h2,
                                            const float* __restrict__ wup,
                                            const float* __restrict__ bup,
                                            float* __restrict__ prob_f) {
    int p = blockIdx.x * 256 + threadIdx.x;
    if (p >= S3) return;
    int pz = p & 31, py = (p >> 5) & 31, px = p >> 10;
    bool occ = pocc[p] != 0;
    float h[16];
    const float* hp = h2 + (size_t)p * 16;
    #pragma unroll
    for (int i = 0; i < 16; i++) h[i] = hp[i];
    #pragma unroll
    for (int o = 0; o < 8; o++) {
        int a = o >> 2, b = (o >> 1) & 1, c = o & 1;
        float* op = prob_f + (((size_t)(2 * px + a) * G + (2 * py + b)) * G + (2 * pz + c)) * 16;
        if (!occ) {
            #pragma unroll
            for (int d = 0; d < 16; d++) op[d] = 0.0f;
        } else {
            #pragma unroll
            for (int d = 0; d < 16; d++) {
                float acc = bup[d];
                #pragma unroll
                for (int cc = 0; cc < 16; cc++)
                    acc = fmaf(h[cc], wup[(o * 16 + cc) * 16 + d], acc);
                op[d] = acc;
            }
        }
    }
}

// ---------------------------------------------------------------- masks + labels
__global__ __launch_bounds__(256) void k_masks(const float* __restrict__ x,
                                               const unsigned char* __restrict__ pocc,
                                               unsigned char* __restrict__ m_in,
                                               unsigned char* __restrict__ m_fin,
                                               float* __restrict__ labels) {
    int v = blockIdx.x * 256 + threadIdx.x;
    if (v >= G3) return;
    int z = v & 63, y = (v >> 6) & 63, xx = v >> 12;
    int par = ((xx & 1) << 2) | ((y & 1) << 1) | (z & 1);
    const int gmap[8] = {0, 5, 4, 3, 4, 2, 1, 5};
    int g = gmap[par];
    int t = ((xx >> 1) + (y >> 1) + (z >> 1)) % 3;
    bool occ = pocc[(((xx >> 1) * S) + (y >> 1)) * S + (z >> 1)] != 0;
    bool ox = x[v] > 0.0f;
    bool g0 = (g == 0);

    bool mi0 = occ && g0 && (t == 0);
    bool mi1 = (occ && g0 && (t == 1)) || (ox && g0 && (t == 0));
    bool mi2 = (ox && g0 && (t < 2)) || (occ && g0 && (t == 2));
    bool mi3 = (ox && g0)       || (occ && (g == 1));
    bool mi4 = (ox && (g <= 1)) || (occ && (g == 2));
    bool mi5 = (ox && (g <= 2)) || (occ && (g == 3));
    bool mi6 = (ox && (g <= 3)) || (occ && (g == 4));
    bool mi7 = (ox && (g <= 4)) || (occ && (g == 5));
    m_in[v] = (unsigned char)(mi0 | (mi1 << 1) | (mi2 << 2) | (mi3 << 3) |
                              (mi4 << 4) | (mi5 << 5) | (mi6 << 6) | (mi7 << 7));

    bool f0 = occ && g0 && (t == 0);
    bool f1 = occ && g0 && (t == 1);
    bool f2 = occ && g0 && (t == 2);
    bool f3 = occ && (g == 1);
    bool f4 = occ && (g == 2);
    bool f5 = occ && (g == 3);
    bool f6 = occ && (g == 4);
    bool f7 = occ && (g == 5);
    m_fin[v] = (unsigned char)(f0 | (f1 << 1) | (f2 << 2) | (f3 << 3) |
                               (f4 << 4) | (f5 << 5) | (f6 << 6) | (f7 << 7));

    labels[0 * (size_t)G3 + v] = (ox && g0 && (t == 0)) ? 1.0f : 0.0f;
    labels[1 * (size_t)G3 + v] = (ox && g0 && (t == 1)) ? 1.0f : 0.0f;
    labels[2 * (size_t)G3 + v] = (ox && g0 && (t == 2)) ? 1.0f : 0.0f;
    labels[3 * (size_t)G3 + v] = (ox && (g == 1)) ? 1.0f : 0.0f;
    labels[4 * (size_t)G3 + v] = (ox && (g == 2)) ? 1.0f : 0.0f;
    labels[5 * (size_t)G3 + v] = (ox && (g == 3)) ? 1.0f : 0.0f;
    labels[6 * (size_t)G3 + v] = (ox && (g == 4)) ? 1.0f : 0.0f;
    labels[7 * (size_t)G3 + v] = (ox && (g == 5)) ? 1.0f : 0.0f;
}

// ---------------------------------------------------------------- coder conv1: C->C, K^3, relu, masked in/out by m_in bit
template <int KS>
__global__ __launch_bounds__(256) void k_conv1(const float* __restrict__ prob_f,
                                               const unsigned char* __restrict__ m_in,
                                               int bit,
                                               const float* __restrict__ w1,
                                               const float* __restrict__ b1,
                                               float* __restrict__ h_buf) {
    const int R = KS / 2;
    int z = threadIdx.x;                       // 0..63 (one wave = one z-line)
    int y = blockIdx.x * blockDim.y + threadIdx.y;
    int xx = blockIdx.y;
    int v = (xx * G + y) * G + z;
    bool m = (m_in[v] >> bit) & 1;
    float acc[16];
    #pragma unroll
    for (int i = 0; i < 16; i++) acc[i] = 0.0f;

    unsigned long long bal = __ballot((int)m);
    if (bal != 0ULL) {
        #pragma unroll
        for (int i = 0; i < 16; i++) acc[i] = b1[i];
        for (int dx = -R; dx <= R; ++dx) {
            int nx = xx + dx; if ((unsigned)nx >= G) continue;
            for (int dy = -R; dy <= R; ++dy) {
                int ny = y + dy; if ((unsigned)ny >= G) continue;
                #pragma unroll
                for (int dz = -R; dz <= R; ++dz) {
                    int nz = z + dz;
                    bool ok = (unsigned)nz < G;
                    int n = (nx * G + ny) * G + (ok ? nz : 0);
                    bool mn = ok && ((m_in[n] >> bit) & 1);
                    if (__any((int)mn)) {
                        const float4* f4 = reinterpret_cast<const float4*>(prob_f + (size_t)n * 16);
                        float4 A = f4[0], B = f4[1], Cc = f4[2], D = f4[3];
                        if (!mn) {
                            A = make_float4(0, 0, 0, 0); B = A; Cc = A; D = A;
                        }
                        float fr[16] = {A.x, A.y, A.z, A.w, B.x, B.y, B.z, B.w,
                                        Cc.x, Cc.y, Cc.z, Cc.w, D.x, D.y, D.z, D.w};
                        const float* w = w1 + (size_t)(((dx + R) * KS + (dy + R)) * KS + (dz + R)) * 256;
                        #pragma unroll
                        for (int ci = 0; ci < 16; ++ci) {
                            float fv = fr[ci];
                            const float* wr = w + ci * 16;
                            #pragma unroll
                            for (int co = 0; co < 16; ++co)
                                acc[co] = fmaf(fv, wr[co], acc[co]);
                        }
                    }
                }
            }
        }
    }
    float* o = h_buf + (size_t)v * 16;
    if (m) {
        #pragma unroll
        for (int co = 0; co < 16; ++co) o[co] = fmaxf(acc[co], 0.0f);
    } else {
        #pragma unroll
        for (int co = 0; co < 16; ++co) o[co] = 0.0f;
    }
}

// ---------------------------------------------------------------- coder conv2: C->1, K^3, sigmoid, masked by final bit
template <int KS>
__global__ __launch_bounds__(256) void k_conv2(const float* __restrict__ h_buf,
                                               const unsigned char* __restrict__ m_fin,
                                               int bit,
                                               const float* __restrict__ w2,
                                               const float* __restrict__ b2,
                                               float* __restrict__ outp) {
    const int R = KS / 2;
    int z = threadIdx.x;
    int y = blockIdx.x * blockDim.y + threadIdx.y;
    int xx = blockIdx.y;
    int v = (xx * G + y) * G + z;
    bool m = (m_fin[v] >> bit) & 1;
    float r = 0.0f;
    unsigned long long bal = __ballot((int)m);
    if (bal != 0ULL) {
        float acc = b2[0];
        for (int dx = -R; dx <= R; ++dx) {
            int nx = xx + dx; if ((unsigned)nx >= G) continue;
            for (int dy = -R; dy <= R; ++dy) {
                int ny = y + dy; if ((unsigned)ny >= G) continue;
                #pragma unroll
                for (int dz = -R; dz <= R; ++dz) {
                    int nz = z + dz;
                    bool ok = (unsigned)nz < G;
                    int n = (nx * G + ny) * G + (ok ? nz : 0);
                    const float* f = h_buf + (size_t)n * 16;
                    const float* w = w2 + (size_t)(((dx + R) * KS + (dy + R)) * KS + (dz + R)) * 16;
                    if (ok) {
                        #pragma unroll
                        for (int ci = 0; ci < 16; ++ci)
                            acc = fmaf(f[ci], w[ci], acc);
                    }
                }
            }
        }
        r = sigmoidf_(acc);
    }
    outp[v] = m ? r : 0.0f;
}

// ---------------------------------------------------------------- launch
extern "C" void kernel_launch(void* const* d_in, const int* in_sizes, int n_in,
                              void* d_out, int out_size, void* d_ws, size_t ws_size,
                              hipStream_t stream) {
    const float* x      = (const float*)d_in[0];
    const float* w_fel1 = (const float*)d_in[3];
    const float* b_fel1 = (const float*)d_in[4];
    const float* w_fel2 = (const float*)d_in[5];
    const float* b_fel2 = (const float*)d_in[6];
    const float* w_up   = (const float*)d_in[7];
    const float* b_up   = (const float*)d_in[8];
    const float* wc1    = (const float*)d_in[9];
    const float* bc1    = (const float*)d_in[10];
    const float* wc2    = (const float*)d_in[11];
    const float* bc2    = (const float*)d_in[12];
    const float* wl1    = (const float*)d_in[13];
    const float* bl1    = (const float*)d_in[14];
    const float* wl2    = (const float*)d_in[15];
    const float* bl2    = (const float*)d_in[16];
    float* out = (float*)d_out;

    char* ws = (char*)d_ws;
    float* prob_f = (float*)(ws);                         // 16 MB
    float* h_buf  = (float*)(ws + 16777216);              // 16 MB
    float* h1     = (float*)(ws + 33554432);              // 2 MB
    float* h2     = (float*)(ws + 35651584);              // 2 MB
    unsigned char* pocc  = (unsigned char*)(ws + 37748736);
    unsigned char* m_in  = (unsigned char*)(ws + 37781504);
    unsigned char* m_fin = (unsigned char*)(ws + 38043648);

    k_pocc<<<dim3(S3 / 256), dim3(256), 0, stream>>>(x, pocc);
    k_fel1<<<dim3(S3 / 256), dim3(256), 0, stream>>>(pocc, w_fel1, b_fel1, h1);
    k_fel2<<<dim3(S3 / 256), dim3(256), 0, stream>>>(pocc, h1, w_fel2, b_fel2, h2);
    k_up  <<<dim3(S3 / 256), dim3(256), 0, stream>>>(pocc, h2, w_up, b_up, prob_f);
    k_masks<<<dim3(G3 / 256), dim3(256), 0, stream>>>(x, pocc, m_in, m_fin, out + (size_t)8 * G3);

    dim3 blk(64, 4, 1);
    dim3 grd(G / 4, G, 1);

    // coder table: {KS, w1, b1, w2, b2}
    struct Coder { int ks; const float* w1; const float* b1; const float* w2; const float* b2; };
    Coder coders[8] = {
        {3, wc1 + 0 * 6912, bc1 + 0 * 16, wc2 + 0 * 432, bc2 + 0},
        {5, wl1 + 0 * 32000, bl1 + 0 * 16, wl2 + 0 * 2000, bl2 + 0},
        {5, wl1 + 1 * 32000, bl1 + 1 * 16, wl2 + 1 * 2000, bl2 + 1},
        {3, wc1 + 1 * 6912, bc1 + 1 * 16, wc2 + 1 * 432, bc2 + 1},
        {3, wc1 + 2 * 6912, bc1 + 2 * 16, wc2 + 2 * 432, bc2 + 2},
        {3, wc1 + 3 * 6912, bc1 + 3 * 16, wc2 + 3 * 432, bc2 + 3},
        {3, wc1 + 4 * 6912, bc1 + 4 * 16, wc2 + 4 * 432, bc2 + 4},
        {3, wc1 + 5 * 6912, bc1 + 5 * 16, wc2 + 5 * 432, bc2 + 5},
    };

    for (int i = 0; i < 8; ++i) {
        float* po = out + (size_t)i * G3;
        if (coders[i].ks == 3) {
            k_conv1<3><<<grd, blk, 0, stream>>>(prob_f, m_in, i, coders[i].w1, coders[i].b1, h_buf);
            k_conv2<3><<<grd, blk, 0, stream>>>(h_buf, m_fin, i, coders[i].w2, coders[i].b2, po);
        } else {
            k_conv1<5><<<grd, blk, 0, stream>>>(prob_f, m_in, i, coders[i].w1, coders[i].b1, h_buf);
            k_conv2<5><<<grd, blk, 0, stream>>>(h_buf, m_fin, i, coders[i].w2, coders[i].b2, po);
        }
    }
}

// Round 2
// 324.981 us; speedup vs baseline: 2.0063x; 2.0063x over previous
//
#include <hip/hip_runtime.h>
#include <cstdint>
#include <math.h>

#define G 64
#define S 32
#define G3 (G*G*G)
#define S3 (S*S*S)

typedef unsigned long long u64;
typedef unsigned int u32;

__device__ __forceinline__ float sigmoidf_(float v) {
    return 1.0f / (1.0f + expf(-v));
}
__device__ __forceinline__ u32 f2bf_rne(float f) {   // round-to-nearest-even bf16 (finite vals)
    u32 u = __float_as_uint(f);
    u += 0x7fff + ((u >> 16) & 1);
    return u >> 16;
}

// ---------------------------------------------------------------- parent occupancy
__global__ __launch_bounds__(256) void k_pocc(const float* __restrict__ x,
                                              unsigned char* __restrict__ pocc) {
    int p = blockIdx.x * 256 + threadIdx.x;
    if (p >= S3) return;
    int pz = p & 31, py = (p >> 5) & 31, px = p >> 10;
    const float* b = x + (((size_t)(px * 2) * G + py * 2) * G + pz * 2);
    bool occ = false;
    #pragma unroll
    for (int a = 0; a < 2; a++)
        #pragma unroll
        for (int bb = 0; bb < 2; bb++)
            #pragma unroll
            for (int c = 0; c < 2; c++)
                occ = occ || (b[((size_t)a * G + bb) * G + c] > 0.0f);
    pocc[p] = occ ? 1 : 0;
}

// ---------------------------------------------------------------- FEL conv1: 1->16, 3^3, relu
__global__ __launch_bounds__(256) void k_fel1(const unsigned char* __restrict__ pocc,
                                              const float* __restrict__ w1,
                                              const float* __restrict__ b1,
                                              float* __restrict__ h1) {
    int p = blockIdx.x * 256 + threadIdx.x;
    if (p >= S3) return;
    int pz = p & 31, py = (p >> 5) & 31, px = p >> 10;
    float* o = h1 + (size_t)p * 16;
    if (!pocc[p]) {
        #pragma unroll
        for (int i = 0; i < 16; i++) o[i] = 0.0f;
        return;
    }
    float acc[16];
    #pragma unroll
    for (int i = 0; i < 16; i++) acc[i] = b1[i];
    for (int dx = -1; dx <= 1; ++dx) {
        int nx = px + dx; if ((unsigned)nx >= S) continue;
        for (int dy = -1; dy <= 1; ++dy) {
            int ny = py + dy; if ((unsigned)ny >= S) continue;
            for (int dz = -1; dz <= 1; ++dz) {
                int nz = pz + dz; if ((unsigned)nz >= S) continue;
                if (pocc[(nx * S + ny) * S + nz]) {
                    const float* w = w1 + (((dx + 1) * 3 + (dy + 1)) * 3 + (dz + 1)) * 16;
                    #pragma unroll
                    for (int i = 0; i < 16; i++) acc[i] += w[i];
                }
            }
        }
    }
    #pragma unroll
    for (int i = 0; i < 16; i++) o[i] = fmaxf(acc[i], 0.0f);
}

// ---------------------------------------------------------------- FEL conv2: 16->16, 3^3
__global__ __launch_bounds__(256) void k_fel2(const unsigned char* __restrict__ pocc,
                                              const float* __restrict__ h1,
                                              const float* __restrict__ w2,
                                              const float* __restrict__ b2,
                                              float* __restrict__ h2) {
    int p = blockIdx.x * 256 + threadIdx.x;
    if (p >= S3) return;
    int pz = p & 31, py = (p >> 5) & 31, px = p >> 10;
    float* o = h2 + (size_t)p * 16;
    if (!pocc[p]) {
        #pragma unroll
        for (int i = 0; i < 16; i++) o[i] = 0.0f;
        return;
    }
    float acc[16];
    #pragma unroll
    for (int i = 0; i < 16; i++) acc[i] = b2[i];
    for (int dx = -1; dx <= 1; ++dx) {
        int nx = px + dx; if ((unsigned)nx >= S) continue;
        for (int dy = -1; dy <= 1; ++dy) {
            int ny = py + dy; if ((unsigned)ny >= S) continue;
            for (int dz = -1; dz <= 1; ++dz) {
                int nz = pz + dz; if ((unsigned)nz >= S) continue;
                const float* f = h1 + (size_t)((nx * S + ny) * S + nz) * 16;
                const float* w = w2 + (((dx + 1) * 3 + (dy + 1)) * 3 + (dz + 1)) * 256;
                #pragma unroll
                for (int ci = 0; ci < 16; ++ci) {
                    float fv = f[ci];
                    #pragma unroll
                    for (int co = 0; co < 16; ++co)
                        acc[co] = fmaf(fv, w[ci * 16 + co], acc[co]);
                }
            }
        }
    }
    #pragma unroll
    for (int i = 0; i < 16; i++) o[i] = acc[i];
}

// ---------------------------------------------------------------- generative up (k2 s2) -> prob_f
__global__ __launch_bounds__(256) void k_up(const unsigned char* __restrict__ pocc,
                                            const float* __restrict__ h2,
                                            const float* __restrict__ wup,
                                            const float* __restrict__ bup,
                                            float* __restrict__ prob_f) {
    int p = blockIdx.x * 256 + threadIdx.x;
    if (p >= S3) return;
    int pz = p & 31, py = (p >> 5) & 31, px = p >> 10;
    bool occ = pocc[p] != 0;
    float h[16];
    const float* hp = h2 + (size_t)p * 16;
    #pragma unroll
    for (int i = 0; i < 16; i++) h[i] = hp[i];
    #pragma unroll
    for (int o = 0; o < 8; o++) {
        int a = o >> 2, b = (o >> 1) & 1, c = o & 1;
        float* op = prob_f + (((size_t)(2 * px + a) * G + (2 * py + b)) * G + (2 * pz + c)) * 16;
        if (!occ) {
            #pragma unroll
            for (int d = 0; d < 16; d++) op[d] = 0.0f;
        } else {
            #pragma unroll
            for (int d = 0; d < 16; d++) {
                float acc = bup[d];
                #pragma unroll
                for (int cc = 0; cc < 16; cc++)
                    acc = fmaf(h[cc], wup[(o * 16 + cc) * 16 + d], acc);
                op[d] = acc;
            }
        }
    }
}

// ---------------------------------------------------------------- masks -> 64-bit line words + labels
__global__ __launch_bounds__(256) void k_masks(const float* __restrict__ x,
                                               const unsigned char* __restrict__ pocc,
                                               u64* __restrict__ lw_in,
                                               u64* __restrict__ lw_fin,
                                               float* __restrict__ labels) {
    int z = threadIdx.x;                 // lane = z
    int y = blockIdx.x * 4 + threadIdx.y;
    int xx = blockIdx.y;
    int v = (xx * G + y) * G + z;
    int par = ((xx & 1) << 2) | ((y & 1) << 1) | (z & 1);
    const int gmap[8] = {0, 5, 4, 3, 4, 2, 1, 5};
    int g = gmap[par];
    int t = ((xx >> 1) + (y >> 1) + (z >> 1)) % 3;
    bool occ = pocc[(((xx >> 1) * S) + (y >> 1)) * S + (z >> 1)] != 0;
    bool ox = x[v] > 0.0f;
    bool g0 = (g == 0);

    bool mi[8], mf[8], lb[8];
    mi[0] = occ && g0 && (t == 0);
    mi[1] = (occ && g0 && (t == 1)) || (ox && g0 && (t == 0));
    mi[2] = (ox && g0 && (t < 2)) || (occ && g0 && (t == 2));
    mi[3] = (ox && g0)       || (occ && (g == 1));
    mi[4] = (ox && (g <= 1)) || (occ && (g == 2));
    mi[5] = (ox && (g <= 2)) || (occ && (g == 3));
    mi[6] = (ox && (g <= 3)) || (occ && (g == 4));
    mi[7] = (ox && (g <= 4)) || (occ && (g == 5));

    mf[0] = occ && g0 && (t == 0);
    mf[1] = occ && g0 && (t == 1);
    mf[2] = occ && g0 && (t == 2);
    mf[3] = occ && (g == 1);
    mf[4] = occ && (g == 2);
    mf[5] = occ && (g == 3);
    mf[6] = occ && (g == 4);
    mf[7] = occ && (g == 5);

    lb[0] = ox && g0 && (t == 0);
    lb[1] = ox && g0 && (t == 1);
    lb[2] = ox && g0 && (t == 2);
    lb[3] = ox && (g == 1);
    lb[4] = ox && (g == 2);
    lb[5] = ox && (g == 3);
    lb[6] = ox && (g == 4);
    lb[7] = ox && (g == 5);

    int line = xx * G + y;
    #pragma unroll
    for (int c = 0; c < 8; ++c) {
        u64 wi = __ballot((int)mi[c]);
        u64 wf = __ballot((int)mf[c]);
        if (z == 0) {
            lw_in[c * 4096 + line] = wi;
            lw_fin[c * 4096 + line] = wf;
        }
        labels[(size_t)c * G3 + v] = lb[c] ? 1.0f : 0.0f;
    }
}

// ---------------------------------------------------------------- coder conv1 body (C->C, K^3, relu)
template <int KS>
__device__ __forceinline__ void conv1_body(const float* __restrict__ prob_f,
                                           const u64* __restrict__ lw,
                                           const float* __restrict__ w1,
                                           const float* __restrict__ b1,
                                           u32* __restrict__ h_c) {
    const int R = KS / 2;
    int z = threadIdx.x;
    int line = blockIdx.x * 4 + threadIdx.y;
    int xx = line >> 6, y = line & 63;
    u64 w0 = lw[line];
    if (w0 == 0ULL) return;                 // whole line has no conv1 outputs
    bool m = (w0 >> z) & 1;

    float acc[16];
    #pragma unroll
    for (int i = 0; i < 16; i++) acc[i] = b1[i];

    for (int dx = -R; dx <= R; ++dx) {
        int nx = xx + dx; if ((unsigned)nx >= G) continue;
        for (int dy = -R; dy <= R; ++dy) {
            int ny = y + dy; if ((unsigned)ny >= G) continue;
            u64 wn = lw[nx * G + ny];
            if (wn == 0ULL) continue;       // parity/occupancy pruning, free
            const float* wbase = w1 + (size_t)(((dx + R) * KS + (dy + R)) * KS) * 256;
            #pragma unroll
            for (int dz = -R; dz <= R; ++dz) {
                int nz = z + dz;
                bool ok = (unsigned)nz < G;
                int nzc = ok ? nz : 0;
                bool mn = ok && ((wn >> nzc) & 1);
                if (!__any((int)mn)) continue;
                const float4* f4 = reinterpret_cast<const float4*>(
                    prob_f + ((size_t)((nx * G + ny) * G + nzc)) * 16);
                float4 A = f4[0], B4 = f4[1], C4 = f4[2], D4 = f4[3];
                if (!mn) { A = make_float4(0, 0, 0, 0); B4 = A; C4 = A; D4 = A; }
                float fr[16] = {A.x, A.y, A.z, A.w, B4.x, B4.y, B4.z, B4.w,
                                C4.x, C4.y, C4.z, C4.w, D4.x, D4.y, D4.z, D4.w};
                const float* w = wbase + (dz + R) * 256;
                #pragma unroll
                for (int ci = 0; ci < 16; ++ci) {
                    float fv = fr[ci];
                    #pragma unroll
                    for (int co = 0; co < 16; ++co)
                        acc[co] = fmaf(fv, w[ci * 16 + co], acc[co]);
                }
            }
        }
    }
    if (m) {
        u32 pk[8];
        #pragma unroll
        for (int i = 0; i < 8; ++i) {
            u32 lo = f2bf_rne(fmaxf(acc[2 * i], 0.0f));
            u32 hi = f2bf_rne(fmaxf(acc[2 * i + 1], 0.0f));
            pk[i] = lo | (hi << 16);
        }
        uint4* o4 = reinterpret_cast<uint4*>(h_c + ((size_t)((xx * G + y) * G + z)) * 8);
        o4[0] = make_uint4(pk[0], pk[1], pk[2], pk[3]);
        o4[1] = make_uint4(pk[4], pk[5], pk[6], pk[7]);
    }
}

// ---------------------------------------------------------------- coder conv2 body (C->1, K^3, sigmoid)
template <int KS>
__device__ __forceinline__ void conv2_body(const u32* __restrict__ h_c,
                                           const u64* __restrict__ lwi,
                                           const u64* __restrict__ lwf,
                                           const float* __restrict__ w2,
                                           const float* __restrict__ b2,
                                           float* __restrict__ outp) {
    const int R = KS / 2;
    int z = threadIdx.x;
    int line = blockIdx.x * 4 + threadIdx.y;
    int xx = line >> 6, y = line & 63;
    int v = (xx * G + y) * G + z;
    u64 wf = lwf[line];
    if (wf == 0ULL) { outp[v] = 0.0f; return; }
    bool m = (wf >> z) & 1;

    float acc = b2[0];
    for (int dx = -R; dx <= R; ++dx) {
        int nx = xx + dx; if ((unsigned)nx >= G) continue;
        for (int dy = -R; dy <= R; ++dy) {
            int ny = y + dy; if ((unsigned)ny >= G) continue;
            u64 wn = lwi[nx * G + ny];
            if (wn == 0ULL) continue;
            const float* wbase = w2 + (size_t)(((dx + R) * KS + (dy + R)) * KS) * 16;
            #pragma unroll
            for (int dz = -R; dz <= R; ++dz) {
                int nz = z + dz;
                bool ok = (unsigned)nz < G;
                int nzc = ok ? nz : 0;
                bool mn = ok && ((wn >> nzc) & 1);
                if (!__any((int)mn)) continue;
                const uint4* h4 = reinterpret_cast<const uint4*>(
                    h_c + ((size_t)((nx * G + ny) * G + nzc)) * 8);
                uint4 Ua = h4[0], Ub = h4[1];
                u32 uu[8] = {Ua.x, Ua.y, Ua.z, Ua.w, Ub.x, Ub.y, Ub.z, Ub.w};
                const float* w = wbase + (dz + R) * 16;
                if (mn) {
                    #pragma unroll
                    for (int i = 0; i < 8; ++i) {
                        float lo = __uint_as_float(uu[i] << 16);
                        float hi = __uint_as_float(uu[i] & 0xffff0000u);
                        acc = fmaf(lo, w[2 * i], acc);
                        acc = fmaf(hi, w[2 * i + 1], acc);
                    }
                }
            }
        }
    }
    outp[v] = m ? sigmoidf_(acc) : 0.0f;
}

// ---------------------------------------------------------------- fused per-coder dispatch wrappers
__global__ __launch_bounds__(256) void k_conv1_all(const float* __restrict__ prob_f,
                                                   const u64* __restrict__ lw_in,
                                                   const float* __restrict__ wc1,
                                                   const float* __restrict__ bc1,
                                                   const float* __restrict__ wl1,
                                                   const float* __restrict__ bl1,
                                                   u32* __restrict__ hbase,
                                                   int coderBase) {
    int c = coderBase + blockIdx.y;
    const u64* lw = lw_in + (size_t)c * 4096;
    u32* h_c = hbase + (size_t)blockIdx.y * G3 * 8;
    if (c == 1 || c == 2) {
        conv1_body<5>(prob_f, lw, wl1 + (size_t)(c - 1) * 32000, bl1 + (c - 1) * 16, h_c);
    } else {
        int j = (c == 0) ? 0 : (c - 2);
        conv1_body<3>(prob_f, lw, wc1 + (size_t)j * 6912, bc1 + j * 16, h_c);
    }
}

__global__ __launch_bounds__(256) void k_conv2_all(const u32* __restrict__ hbase,
                                                   const u64* __restrict__ lw_in,
                                                   const u64* __restrict__ lw_fin,
                                                   const float* __restrict__ wc2,
                                                   const float* __restrict__ bc2,
                                                   const float* __restrict__ wl2,
                                                   const float* __restrict__ bl2,
                                                   float* __restrict__ out,
                                                   int coderBase) {
    int c = coderBase + blockIdx.y;
    const u64* lwi = lw_in + (size_t)c * 4096;
    const u64* lwf = lw_fin + (size_t)c * 4096;
    const u32* h_c = hbase + (size_t)blockIdx.y * G3 * 8;
    float* outp = out + (size_t)c * G3;
    if (c == 1 || c == 2) {
        conv2_body<5>(h_c, lwi, lwf, wl2 + (size_t)(c - 1) * 2000, bl2 + (c - 1), outp);
    } else {
        int j = (c == 0) ? 0 : (c - 2);
        conv2_body<3>(h_c, lwi, lwf, wc2 + (size_t)j * 432, bc2 + j, outp);
    }
}

// ---------------------------------------------------------------- launch
extern "C" void kernel_launch(void* const* d_in, const int* in_sizes, int n_in,
                              void* d_out, int out_size, void* d_ws, size_t ws_size,
                              hipStream_t stream) {
    const float* x      = (const float*)d_in[0];
    const float* w_fel1 = (const float*)d_in[3];
    const float* b_fel1 = (const float*)d_in[4];
    const float* w_fel2 = (const float*)d_in[5];
    const float* b_fel2 = (const float*)d_in[6];
    const float* w_up   = (const float*)d_in[7];
    const float* b_up   = (const float*)d_in[8];
    const float* wc1    = (const float*)d_in[9];
    const float* bc1    = (const float*)d_in[10];
    const float* wc2    = (const float*)d_in[11];
    const float* bc2    = (const float*)d_in[12];
    const float* wl1    = (const float*)d_in[13];
    const float* bl1    = (const float*)d_in[14];
    const float* wl2    = (const float*)d_in[15];
    const float* bl2    = (const float*)d_in[16];
    float* out = (float*)d_out;

    char* ws = (char*)d_ws;
    float* prob_f = (float*)(ws);                          // 16 MB
    float* h1     = (float*)(ws + 16777216);               // 2 MB
    float* h2     = (float*)(ws + 18874368);               // 2 MB
    unsigned char* pocc = (unsigned char*)(ws + 20971520); // 32 KB
    u64* lw_in  = (u64*)(ws + 21004288);                   // 256 KB
    u64* lw_fin = (u64*)(ws + 21266432);                   // 256 KB
    u32* hbase  = (u32*)(ws + 21528576);                   // B * 8 MB (bf16 h, packed as u32 pairs)

    const size_t fixed_end = 21528576;
    const size_t hsz = (size_t)G3 * 16 * 2;                // 8 MB per coder
    int B = 2;                                             // 38.3 MB — proven-safe floor
    if (fixed_end + 8 * hsz <= ws_size) B = 8;
    else if (fixed_end + 4 * hsz <= ws_size) B = 4;

    k_pocc <<<dim3(S3 / 256), dim3(256), 0, stream>>>(x, pocc);
    k_fel1 <<<dim3(S3 / 256), dim3(256), 0, stream>>>(pocc, w_fel1, b_fel1, h1);
    k_fel2 <<<dim3(S3 / 256), dim3(256), 0, stream>>>(pocc, h1, w_fel2, b_fel2, h2);
    k_up   <<<dim3(S3 / 256), dim3(256), 0, stream>>>(pocc, h2, w_up, b_up, prob_f);
    k_masks<<<dim3(16, 64), dim3(64, 4), 0, stream>>>(x, pocc, lw_in, lw_fin, out + (size_t)8 * G3);

    for (int b0 = 0; b0 < 8; b0 += B) {
        int nb = (8 - b0 < B) ? (8 - b0) : B;
        k_conv1_all<<<dim3(1024, nb), dim3(64, 4), 0, stream>>>(
            prob_f, lw_in, wc1, bc1, wl1, bl1, hbase, b0);
        k_conv2_all<<<dim3(1024, nb), dim3(64, 4), 0, stream>>>(
            hbase, lw_in, lw_fin, wc2, bc2, wl2, bl2, out, b0);
    }
}

// Round 3
// 258.839 us; speedup vs baseline: 2.5189x; 1.2555x over previous
//
#include <hip/hip_runtime.h>
#include <cstdint>
#include <math.h>

#define G 64
#define S 32
#define G3 (G*G*G)
#define S3 (S*S*S)

typedef unsigned long long u64;
typedef unsigned int u32;

__device__ __forceinline__ float sigmoidf_(float v) {
    return 1.0f / (1.0f + expf(-v));
}
__device__ __forceinline__ u32 f2bf_rne(float f) {   // round-to-nearest-even bf16 (finite vals)
    u32 u = __float_as_uint(f);
    u += 0x7fff + ((u >> 16) & 1);
    return u >> 16;
}

// ---------------------------------------------------------------- parent occupancy
__global__ __launch_bounds__(256) void k_pocc(const float* __restrict__ x,
                                              unsigned char* __restrict__ pocc) {
    int p = blockIdx.x * 256 + threadIdx.x;
    if (p >= S3) return;
    int pz = p & 31, py = (p >> 5) & 31, px = p >> 10;
    const float* b = x + (((size_t)(px * 2) * G + py * 2) * G + pz * 2);
    bool occ = false;
    #pragma unroll
    for (int a = 0; a < 2; a++)
        #pragma unroll
        for (int bb = 0; bb < 2; bb++)
            #pragma unroll
            for (int c = 0; c < 2; c++)
                occ = occ || (b[((size_t)a * G + bb) * G + c] > 0.0f);
    pocc[p] = occ ? 1 : 0;
}

// ---------------------------------------------------------------- FEL conv1: 1->16, 3^3, relu
__global__ __launch_bounds__(256) void k_fel1(const unsigned char* __restrict__ pocc,
                                              const float* __restrict__ w1,
                                              const float* __restrict__ b1,
                                              float* __restrict__ h1) {
    int p = blockIdx.x * 256 + threadIdx.x;
    if (p >= S3) return;
    int pz = p & 31, py = (p >> 5) & 31, px = p >> 10;
    float* o = h1 + (size_t)p * 16;
    if (!pocc[p]) {
        #pragma unroll
        for (int i = 0; i < 16; i++) o[i] = 0.0f;
        return;
    }
    float acc[16];
    #pragma unroll
    for (int i = 0; i < 16; i++) acc[i] = b1[i];
    for (int dx = -1; dx <= 1; ++dx) {
        int nx = px + dx; if ((unsigned)nx >= S) continue;
        for (int dy = -1; dy <= 1; ++dy) {
            int ny = py + dy; if ((unsigned)ny >= S) continue;
            for (int dz = -1; dz <= 1; ++dz) {
                int nz = pz + dz; if ((unsigned)nz >= S) continue;
                if (pocc[(nx * S + ny) * S + nz]) {
                    const float* w = w1 + (((dx + 1) * 3 + (dy + 1)) * 3 + (dz + 1)) * 16;
                    #pragma unroll
                    for (int i = 0; i < 16; i++) acc[i] += w[i];
                }
            }
        }
    }
    #pragma unroll
    for (int i = 0; i < 16; i++) o[i] = fmaxf(acc[i], 0.0f);
}

// ---------------------------------------------------------------- FEL conv2: 16->16, 3^3
__global__ __launch_bounds__(256) void k_fel2(const unsigned char* __restrict__ pocc,
                                              const float* __restrict__ h1,
                                              const float* __restrict__ w2,
                                              const float* __restrict__ b2,
                                              float* __restrict__ h2) {
    int p = blockIdx.x * 256 + threadIdx.x;
    if (p >= S3) return;
    int pz = p & 31, py = (p >> 5) & 31, px = p >> 10;
    float* o = h2 + (size_t)p * 16;
    if (!pocc[p]) {
        #pragma unroll
        for (int i = 0; i < 16; i++) o[i] = 0.0f;
        return;
    }
    float acc[16];
    #pragma unroll
    for (int i = 0; i < 16; i++) acc[i] = b2[i];
    for (int dx = -1; dx <= 1; ++dx) {
        int nx = px + dx; if ((unsigned)nx >= S) continue;
        for (int dy = -1; dy <= 1; ++dy) {
            int ny = py + dy; if ((unsigned)ny >= S) continue;
            for (int dz = -1; dz <= 1; ++dz) {
                int nz = pz + dz; if ((unsigned)nz >= S) continue;
                const float* f = h1 + (size_t)((nx * S + ny) * S + nz) * 16;
                const float* w = w2 + (((dx + 1) * 3 + (dy + 1)) * 3 + (dz + 1)) * 256;
                #pragma unroll
                for (int ci = 0; ci < 16; ++ci) {
                    float fv = f[ci];
                    #pragma unroll
                    for (int co = 0; co < 16; ++co)
                        acc[co] = fmaf(fv, w[ci * 16 + co], acc[co]);
                }
            }
        }
    }
    #pragma unroll
    for (int i = 0; i < 16; i++) o[i] = acc[i];
}

// ---------------------------------------------------------------- generative up (k2 s2) -> prob_f
__global__ __launch_bounds__(256) void k_up(const unsigned char* __restrict__ pocc,
                                            const float* __restrict__ h2,
                                            const float* __restrict__ wup,
                                            const float* __restrict__ bup,
                                            float* __restrict__ prob_f) {
    int p = blockIdx.x * 256 + threadIdx.x;
    if (p >= S3) return;
    int pz = p & 31, py = (p >> 5) & 31, px = p >> 10;
    bool occ = pocc[p] != 0;
    float h[16];
    const float* hp = h2 + (size_t)p * 16;
    #pragma unroll
    for (int i = 0; i < 16; i++) h[i] = hp[i];
    #pragma unroll
    for (int o = 0; o < 8; o++) {
        int a = o >> 2, b = (o >> 1) & 1, c = o & 1;
        float* op = prob_f + (((size_t)(2 * px + a) * G + (2 * py + b)) * G + (2 * pz + c)) * 16;
        if (!occ) {
            #pragma unroll
            for (int d = 0; d < 16; d++) op[d] = 0.0f;
        } else {
            #pragma unroll
            for (int d = 0; d < 16; d++) {
                float acc = bup[d];
                #pragma unroll
                for (int cc = 0; cc < 16; cc++)
                    acc = fmaf(h[cc], wup[(o * 16 + cc) * 16 + d], acc);
                op[d] = acc;
            }
        }
    }
}

// ---------------------------------------------------------------- masks -> 64-bit line words + labels
__global__ __launch_bounds__(256) void k_masks(const float* __restrict__ x,
                                               const unsigned char* __restrict__ pocc,
                                               u64* __restrict__ lw_in,
                                               u64* __restrict__ lw_fin,
                                               float* __restrict__ labels) {
    int z = threadIdx.x;                 // lane = z
    int y = blockIdx.x * 4 + threadIdx.y;
    int xx = blockIdx.y;
    int v = (xx * G + y) * G + z;
    int par = ((xx & 1) << 2) | ((y & 1) << 1) | (z & 1);
    const int gmap[8] = {0, 5, 4, 3, 4, 2, 1, 5};
    int g = gmap[par];
    int t = ((xx >> 1) + (y >> 1) + (z >> 1)) % 3;
    bool occ = pocc[(((xx >> 1) * S) + (y >> 1)) * S + (z >> 1)] != 0;
    bool ox = x[v] > 0.0f;
    bool g0 = (g == 0);

    bool mi[8], mf[8], lb[8];
    mi[0] = occ && g0 && (t == 0);
    mi[1] = (occ && g0 && (t == 1)) || (ox && g0 && (t == 0));
    mi[2] = (ox && g0 && (t < 2)) || (occ && g0 && (t == 2));
    mi[3] = (ox && g0)       || (occ && (g == 1));
    mi[4] = (ox && (g <= 1)) || (occ && (g == 2));
    mi[5] = (ox && (g <= 2)) || (occ && (g == 3));
    mi[6] = (ox && (g <= 3)) || (occ && (g == 4));
    mi[7] = (ox && (g <= 4)) || (occ && (g == 5));

    mf[0] = occ && g0 && (t == 0);
    mf[1] = occ && g0 && (t == 1);
    mf[2] = occ && g0 && (t == 2);
    mf[3] = occ && (g == 1);
    mf[4] = occ && (g == 2);
    mf[5] = occ && (g == 3);
    mf[6] = occ && (g == 4);
    mf[7] = occ && (g == 5);

    lb[0] = ox && g0 && (t == 0);
    lb[1] = ox && g0 && (t == 1);
    lb[2] = ox && g0 && (t == 2);
    lb[3] = ox && (g == 1);
    lb[4] = ox && (g == 2);
    lb[5] = ox && (g == 3);
    lb[6] = ox && (g == 4);
    lb[7] = ox && (g == 5);

    int line = xx * G + y;
    #pragma unroll
    for (int c = 0; c < 8; ++c) {
        u64 wi = __ballot((int)mi[c]);
        u64 wf = __ballot((int)mf[c]);
        if (z == 0) {
            lw_in[c * 4096 + line] = wi;
            lw_fin[c * 4096 + line] = wf;
        }
        labels[(size_t)c * G3 + v] = lb[c] ? 1.0f : 0.0f;
    }
}

// exact tap-usefulness: bits z where OUTPUT bit z set AND neighbor bit z+dz set
__device__ __forceinline__ u64 tap_hit(u64 wout, u64 wn, int dz) {
    return (dz >= 0) ? (wout & (wn >> dz)) : (wout & (wn << (-dz)));
}

// ---------------------------------------------------------------- coder conv1 body (C->C, K^3, relu)
template <int KS>
__device__ __forceinline__ void conv1_body(const float* __restrict__ prob_f,
                                           const u64* __restrict__ lw,
                                           const float* __restrict__ w1,
                                           const float* __restrict__ b1,
                                           u32* __restrict__ h_c) {
    const int R = KS / 2;
    int z = threadIdx.x;
    int line = blockIdx.x * 4 + threadIdx.y;
    int xx = line >> 6, y = line & 63;
    u64 w0 = lw[line];
    if (w0 == 0ULL) return;                 // whole line has no conv1 outputs
    bool m = (w0 >> z) & 1;

    float acc[16];
    #pragma unroll
    for (int i = 0; i < 16; i++) acc[i] = b1[i];

    for (int dx = -R; dx <= R; ++dx) {
        int nx = xx + dx; if ((unsigned)nx >= G) continue;
        for (int dy = -R; dy <= R; ++dy) {
            int ny = y + dy; if ((unsigned)ny >= G) continue;
            u64 wn = lw[nx * G + ny];
            if (wn == 0ULL) continue;       // parity/occupancy pruning (scalar)
            const float* wbase = w1 + (size_t)(((dx + R) * KS + (dy + R)) * KS) * 256;
            #pragma unroll
            for (int dz = -R; dz <= R; ++dz) {
                if (tap_hit(w0, wn, dz) == 0ULL) continue;   // exact scalar prune
                int nz = z + dz;
                bool ok = (unsigned)nz < G;
                int nzc = ok ? nz : 0;
                bool mn = ok && ((wn >> nzc) & 1);
                const float4* f4 = reinterpret_cast<const float4*>(
                    prob_f + ((size_t)((nx * G + ny) * G + nzc)) * 16);
                float4 A = f4[0], B4 = f4[1], C4 = f4[2], D4 = f4[3];
                if (!mn) { A = make_float4(0, 0, 0, 0); B4 = A; C4 = A; D4 = A; }
                float fr[16] = {A.x, A.y, A.z, A.w, B4.x, B4.y, B4.z, B4.w,
                                C4.x, C4.y, C4.z, C4.w, D4.x, D4.y, D4.z, D4.w};
                const float* w = wbase + (dz + R) * 256;
                #pragma unroll
                for (int ci = 0; ci < 16; ++ci) {
                    float fv = fr[ci];
                    #pragma unroll
                    for (int co = 0; co < 16; ++co)
                        acc[co] = fmaf(fv, w[ci * 16 + co], acc[co]);
                }
            }
        }
    }
    if (m) {
        u32 pk[8];
        #pragma unroll
        for (int i = 0; i < 8; ++i) {
            u32 lo = f2bf_rne(fmaxf(acc[2 * i], 0.0f));
            u32 hi = f2bf_rne(fmaxf(acc[2 * i + 1], 0.0f));
            pk[i] = lo | (hi << 16);
        }
        uint4* o4 = reinterpret_cast<uint4*>(h_c + ((size_t)((xx * G + y) * G + z)) * 8);
        o4[0] = make_uint4(pk[0], pk[1], pk[2], pk[3]);
        o4[1] = make_uint4(pk[4], pk[5], pk[6], pk[7]);
    }
}

// ---------------------------------------------------------------- coder conv2 body (C->1, K^3, sigmoid)
template <int KS>
__device__ __forceinline__ void conv2_body(const u32* __restrict__ h_c,
                                           const u64* __restrict__ lwi,
                                           const u64* __restrict__ lwf,
                                           const float* __restrict__ w2,
                                           const float* __restrict__ b2,
                                           float* __restrict__ outp) {
    const int R = KS / 2;
    int z = threadIdx.x;
    int line = blockIdx.x * 4 + threadIdx.y;
    int xx = line >> 6, y = line & 63;
    int v = (xx * G + y) * G + z;
    u64 wf = lwf[line];
    if (wf == 0ULL) { outp[v] = 0.0f; return; }
    bool m = (wf >> z) & 1;

    float acc = b2[0];
    for (int dx = -R; dx <= R; ++dx) {
        int nx = xx + dx; if ((unsigned)nx >= G) continue;
        for (int dy = -R; dy <= R; ++dy) {
            int ny = y + dy; if ((unsigned)ny >= G) continue;
            u64 wn = lwi[nx * G + ny];
            if (wn == 0ULL) continue;
            const float* wbase = w2 + (size_t)(((dx + R) * KS + (dy + R)) * KS) * 16;
            #pragma unroll
            for (int dz = -R; dz <= R; ++dz) {
                if (tap_hit(wf, wn, dz) == 0ULL) continue;   // exact scalar prune
                int nz = z + dz;
                bool ok = (unsigned)nz < G;
                int nzc = ok ? nz : 0;
                bool mn = ok && ((wn >> nzc) & 1);
                const uint4* h4 = reinterpret_cast<const uint4*>(
                    h_c + ((size_t)((nx * G + ny) * G + nzc)) * 8);
                uint4 Ua = h4[0], Ub = h4[1];
                u32 uu[8] = {Ua.x, Ua.y, Ua.z, Ua.w, Ub.x, Ub.y, Ub.z, Ub.w};
                const float* w = wbase + (dz + R) * 16;
                if (mn) {
                    #pragma unroll
                    for (int i = 0; i < 8; ++i) {
                        float lo = __uint_as_float(uu[i] << 16);
                        float hi = __uint_as_float(uu[i] & 0xffff0000u);
                        acc = fmaf(lo, w[2 * i], acc);
                        acc = fmaf(hi, w[2 * i + 1], acc);
                    }
                }
            }
        }
    }
    outp[v] = m ? sigmoidf_(acc) : 0.0f;
}

// ---------------------------------------------------------------- fused per-coder dispatch wrappers
__global__ __launch_bounds__(256) void k_conv1_all(const float* __restrict__ prob_f,
                                                   const u64* __restrict__ lw_in,
                                                   const float* __restrict__ wc1,
                                                   const float* __restrict__ bc1,
                                                   const float* __restrict__ wl1,
                                                   const float* __restrict__ bl1,
                                                   u32* __restrict__ hbase,
                                                   int coderBase) {
    int c = coderBase + blockIdx.y;
    const u64* lw = lw_in + (size_t)c * 4096;
    u32* h_c = hbase + (size_t)blockIdx.y * G3 * 8;
    if (c == 1 || c == 2) {
        conv1_body<5>(prob_f, lw, wl1 + (size_t)(c - 1) * 32000, bl1 + (c - 1) * 16, h_c);
    } else {
        int j = (c == 0) ? 0 : (c - 2);
        conv1_body<3>(prob_f, lw, wc1 + (size_t)j * 6912, bc1 + j * 16, h_c);
    }
}

__global__ __launch_bounds__(256) void k_conv2_all(const u32* __restrict__ hbase,
                                                   const u64* __restrict__ lw_in,
                                                   const u64* __restrict__ lw_fin,
                                                   const float* __restrict__ wc2,
                                                   const float* __restrict__ bc2,
                                                   const float* __restrict__ wl2,
                                                   const float* __restrict__ bl2,
                                                   float* __restrict__ out,
                                                   int coderBase) {
    int c = coderBase + blockIdx.y;
    const u64* lwi = lw_in + (size_t)c * 4096;
    const u64* lwf = lw_fin + (size_t)c * 4096;
    const u32* h_c = hbase + (size_t)blockIdx.y * G3 * 8;
    float* outp = out + (size_t)c * G3;
    if (c == 1 || c == 2) {
        conv2_body<5>(h_c, lwi, lwf, wl2 + (size_t)(c - 1) * 2000, bl2 + (c - 1), outp);
    } else {
        int j = (c == 0) ? 0 : (c - 2);
        conv2_body<3>(h_c, lwi, lwf, wc2 + (size_t)j * 432, bc2 + j, outp);
    }
}

// ---------------------------------------------------------------- launch
extern "C" void kernel_launch(void* const* d_in, const int* in_sizes, int n_in,
                              void* d_out, int out_size, void* d_ws, size_t ws_size,
                              hipStream_t stream) {
    const float* x      = (const float*)d_in[0];
    const float* w_fel1 = (const float*)d_in[3];
    const float* b_fel1 = (const float*)d_in[4];
    const float* w_fel2 = (const float*)d_in[5];
    const float* b_fel2 = (const float*)d_in[6];
    const float* w_up   = (const float*)d_in[7];
    const float* b_up   = (const float*)d_in[8];
    const float* wc1    = (const float*)d_in[9];
    const float* bc1    = (const float*)d_in[10];
    const float* wc2    = (const float*)d_in[11];
    const float* bc2    = (const float*)d_in[12];
    const float* wl1    = (const float*)d_in[13];
    const float* bl1    = (const float*)d_in[14];
    const float* wl2    = (const float*)d_in[15];
    const float* bl2    = (const float*)d_in[16];
    float* out = (float*)d_out;

    char* ws = (char*)d_ws;
    float* prob_f = (float*)(ws);                          // 16 MB
    float* h1     = (float*)(ws + 16777216);               // 2 MB
    float* h2     = (float*)(ws + 18874368);               // 2 MB
    unsigned char* pocc = (unsigned char*)(ws + 20971520); // 32 KB
    u64* lw_in  = (u64*)(ws + 21004288);                   // 256 KB
    u64* lw_fin = (u64*)(ws + 21266432);                   // 256 KB
    u32* hbase  = (u32*)(ws + 21528576);                   // B * 8 MB (bf16 h, packed as u32 pairs)

    const size_t fixed_end = 21528576;
    const size_t hsz = (size_t)G3 * 16 * 2;                // 8 MB per coder
    int B = 2;                                             // 38.3 MB — proven-safe floor
    if (fixed_end + 8 * hsz <= ws_size) B = 8;
    else if (fixed_end + 4 * hsz <= ws_size) B = 4;

    k_pocc <<<dim3(S3 / 256), dim3(256), 0, stream>>>(x, pocc);
    k_fel1 <<<dim3(S3 / 256), dim3(256), 0, stream>>>(pocc, w_fel1, b_fel1, h1);
    k_fel2 <<<dim3(S3 / 256), dim3(256), 0, stream>>>(pocc, h1, w_fel2, b_fel2, h2);
    k_up   <<<dim3(S3 / 256), dim3(256), 0, stream>>>(pocc, h2, w_up, b_up, prob_f);
    k_masks<<<dim3(16, 64), dim3(64, 4), 0, stream>>>(x, pocc, lw_in, lw_fin, out + (size_t)8 * G3);

    for (int b0 = 0; b0 < 8; b0 += B) {
        int nb = (8 - b0 < B) ? (8 - b0) : B;
        k_conv1_all<<<dim3(1024, nb), dim3(64, 4), 0, stream>>>(
            prob_f, lw_in, wc1, bc1, wl1, bl1, hbase, b0);
        k_conv2_all<<<dim3(1024, nb), dim3(64, 4), 0, stream>>>(
            hbase, lw_in, lw_fin, wc2, bc2, wl2, bl2, out, b0);
    }
}

// Round 4
// 212.131 us; speedup vs baseline: 3.0736x; 1.2202x over previous
//
#include <hip/hip_runtime.h>
#include <cstdint>
#include <math.h>

#define G 64
#define S 32
#define G3 (G*G*G)
#define S3 (S*S*S)

typedef unsigned long long u64;
typedef unsigned int u32;
typedef unsigned short u16;

typedef __attribute__((ext_vector_type(8))) short s16x8;   // 8 bf16 (4 VGPRs)
typedef __attribute__((ext_vector_type(4))) float f32x4;   // MFMA acc

__device__ __forceinline__ float sigmoidf_(float v) {
    return 1.0f / (1.0f + expf(-v));
}
__device__ __forceinline__ u32 f2bf_rne(float f) {   // round-to-nearest-even bf16
    u32 u = __float_as_uint(f);
    u += 0x7fff + ((u >> 16) & 1);
    return u >> 16;
}
__device__ __forceinline__ u64 rfl64(u64 v) {
    u32 lo = __builtin_amdgcn_readfirstlane((u32)v);
    u32 hi = __builtin_amdgcn_readfirstlane((u32)(v >> 32));
    return ((u64)hi << 32) | lo;
}
// exact tap-usefulness: bits z where OUTPUT bit z set AND neighbor bit z+dz set
__device__ __forceinline__ u64 tap_hit(u64 wout, u64 wn, int dz) {
    return (dz >= 0) ? (wout & (wn >> dz)) : (wout & (wn << (-dz)));
}

// ---------------------------------------------------------------- parent occupancy
__global__ __launch_bounds__(256) void k_pocc(const float* __restrict__ x,
                                              unsigned char* __restrict__ pocc) {
    int p = blockIdx.x * 256 + threadIdx.x;
    if (p >= S3) return;
    int pz = p & 31, py = (p >> 5) & 31, px = p >> 10;
    const float* b = x + (((size_t)(px * 2) * G + py * 2) * G + pz * 2);
    bool occ = false;
    #pragma unroll
    for (int a = 0; a < 2; a++)
        #pragma unroll
        for (int bb = 0; bb < 2; bb++)
            #pragma unroll
            for (int c = 0; c < 2; c++)
                occ = occ || (b[((size_t)a * G + bb) * G + c] > 0.0f);
    pocc[p] = occ ? 1 : 0;
}

// ---------------------------------------------------------------- FEL conv1: 1->16, 3^3, relu
__global__ __launch_bounds__(256) void k_fel1(const unsigned char* __restrict__ pocc,
                                              const float* __restrict__ w1,
                                              const float* __restrict__ b1,
                                              float* __restrict__ h1) {
    int p = blockIdx.x * 256 + threadIdx.x;
    if (p >= S3) return;
    int pz = p & 31, py = (p >> 5) & 31, px = p >> 10;
    float* o = h1 + (size_t)p * 16;
    if (!pocc[p]) {
        #pragma unroll
        for (int i = 0; i < 16; i++) o[i] = 0.0f;
        return;
    }
    float acc[16];
    #pragma unroll
    for (int i = 0; i < 16; i++) acc[i] = b1[i];
    for (int dx = -1; dx <= 1; ++dx) {
        int nx = px + dx; if ((unsigned)nx >= S) continue;
        for (int dy = -1; dy <= 1; ++dy) {
            int ny = py + dy; if ((unsigned)ny >= S) continue;
            for (int dz = -1; dz <= 1; ++dz) {
                int nz = pz + dz; if ((unsigned)nz >= S) continue;
                if (pocc[(nx * S + ny) * S + nz]) {
                    const float* w = w1 + (((dx + 1) * 3 + (dy + 1)) * 3 + (dz + 1)) * 16;
                    #pragma unroll
                    for (int i = 0; i < 16; i++) acc[i] += w[i];
                }
            }
        }
    }
    #pragma unroll
    for (int i = 0; i < 16; i++) o[i] = fmaxf(acc[i], 0.0f);
}

// ---------------------------------------------------------------- FEL conv2: 16->16, 3^3
__global__ __launch_bounds__(256) void k_fel2(const unsigned char* __restrict__ pocc,
                                              const float* __restrict__ h1,
                                              const float* __restrict__ w2,
                                              const float* __restrict__ b2,
                                              float* __restrict__ h2) {
    int p = blockIdx.x * 256 + threadIdx.x;
    if (p >= S3) return;
    int pz = p & 31, py = (p >> 5) & 31, px = p >> 10;
    float* o = h2 + (size_t)p * 16;
    if (!pocc[p]) {
        #pragma unroll
        for (int i = 0; i < 16; i++) o[i] = 0.0f;
        return;
    }
    float acc[16];
    #pragma unroll
    for (int i = 0; i < 16; i++) acc[i] = b2[i];
    for (int dx = -1; dx <= 1; ++dx) {
        int nx = px + dx; if ((unsigned)nx >= S) continue;
        for (int dy = -1; dy <= 1; ++dy) {
            int ny = py + dy; if ((unsigned)ny >= S) continue;
            for (int dz = -1; dz <= 1; ++dz) {
                int nz = pz + dz; if ((unsigned)nz >= S) continue;
                const float* f = h1 + (size_t)((nx * S + ny) * S + nz) * 16;
                const float* w = w2 + (((dx + 1) * 3 + (dy + 1)) * 3 + (dz + 1)) * 256;
                #pragma unroll
                for (int ci = 0; ci < 16; ++ci) {
                    float fv = f[ci];
                    #pragma unroll
                    for (int co = 0; co < 16; ++co)
                        acc[co] = fmaf(fv, w[ci * 16 + co], acc[co]);
                }
            }
        }
    }
    #pragma unroll
    for (int i = 0; i < 16; i++) o[i] = acc[i];
}

// ---------------------------------------------------------------- generative up (k2 s2) -> prob_f (bf16)
__global__ __launch_bounds__(256) void k_up(const unsigned char* __restrict__ pocc,
                                            const float* __restrict__ h2,
                                            const float* __restrict__ wup,
                                            const float* __restrict__ bup,
                                            u16* __restrict__ probf16) {
    int p = blockIdx.x * 256 + threadIdx.x;
    if (p >= S3) return;
    int pz = p & 31, py = (p >> 5) & 31, px = p >> 10;
    bool occ = pocc[p] != 0;
    float h[16];
    const float* hp = h2 + (size_t)p * 16;
    #pragma unroll
    for (int i = 0; i < 16; i++) h[i] = hp[i];
    #pragma unroll
    for (int o = 0; o < 8; o++) {
        int a = o >> 2, b = (o >> 1) & 1, c = o & 1;
        u16* op = probf16 + (((size_t)(2 * px + a) * G + (2 * py + b)) * G + (2 * pz + c)) * 16;
        uint4* o4 = reinterpret_cast<uint4*>(op);
        if (!occ) {
            o4[0] = make_uint4(0, 0, 0, 0);
            o4[1] = make_uint4(0, 0, 0, 0);
        } else {
            u32 pk[8];
            #pragma unroll
            for (int i = 0; i < 8; ++i) {
                float a0 = bup[2 * i], a1 = bup[2 * i + 1];
                #pragma unroll
                for (int cc = 0; cc < 16; cc++) {
                    a0 = fmaf(h[cc], wup[(o * 16 + cc) * 16 + 2 * i], a0);
                    a1 = fmaf(h[cc], wup[(o * 16 + cc) * 16 + 2 * i + 1], a1);
                }
                pk[i] = f2bf_rne(a0) | (f2bf_rne(a1) << 16);
            }
            o4[0] = make_uint4(pk[0], pk[1], pk[2], pk[3]);
            o4[1] = make_uint4(pk[4], pk[5], pk[6], pk[7]);
        }
    }
}

// ---------------------------------------------------------------- masks -> 64-bit line words + labels
__global__ __launch_bounds__(256) void k_masks(const float* __restrict__ x,
                                               const unsigned char* __restrict__ pocc,
                                               u64* __restrict__ lw_in,
                                               u64* __restrict__ lw_fin,
                                               float* __restrict__ labels) {
    int z = threadIdx.x;
    int y = blockIdx.x * 4 + threadIdx.y;
    int xx = blockIdx.y;
    int v = (xx * G + y) * G + z;
    int par = ((xx & 1) << 2) | ((y & 1) << 1) | (z & 1);
    const int gmap[8] = {0, 5, 4, 3, 4, 2, 1, 5};
    int g = gmap[par];
    int t = ((xx >> 1) + (y >> 1) + (z >> 1)) % 3;
    bool occ = pocc[(((xx >> 1) * S) + (y >> 1)) * S + (z >> 1)] != 0;
    bool ox = x[v] > 0.0f;
    bool g0 = (g == 0);

    bool mi[8], mf[8], lb[8];
    mi[0] = occ && g0 && (t == 0);
    mi[1] = (occ && g0 && (t == 1)) || (ox && g0 && (t == 0));
    mi[2] = (ox && g0 && (t < 2)) || (occ && g0 && (t == 2));
    mi[3] = (ox && g0)       || (occ && (g == 1));
    mi[4] = (ox && (g <= 1)) || (occ && (g == 2));
    mi[5] = (ox && (g <= 2)) || (occ && (g == 3));
    mi[6] = (ox && (g <= 3)) || (occ && (g == 4));
    mi[7] = (ox && (g <= 4)) || (occ && (g == 5));

    mf[0] = occ && g0 && (t == 0);
    mf[1] = occ && g0 && (t == 1);
    mf[2] = occ && g0 && (t == 2);
    mf[3] = occ && (g == 1);
    mf[4] = occ && (g == 2);
    mf[5] = occ && (g == 3);
    mf[6] = occ && (g == 4);
    mf[7] = occ && (g == 5);

    lb[0] = ox && g0 && (t == 0);
    lb[1] = ox && g0 && (t == 1);
    lb[2] = ox && g0 && (t == 2);
    lb[3] = ox && (g == 1);
    lb[4] = ox && (g == 2);
    lb[5] = ox && (g == 3);
    lb[6] = ox && (g == 4);
    lb[7] = ox && (g == 5);

    int line = xx * G + y;
    #pragma unroll
    for (int c = 0; c < 8; ++c) {
        u64 wi = __ballot((int)mi[c]);
        u64 wf = __ballot((int)mf[c]);
        if (z == 0) {
            lw_in[c * 4096 + line] = wi;
            lw_fin[c * 4096 + line] = wf;
        }
        labels[(size_t)c * G3 + v] = lb[c] ? 1.0f : 0.0f;
    }
}

// ---------------------------------------------------------------- B-fragment prep (weights -> MFMA lane layout, bf16)
// frag index = ((dxi*KS)+dyi)*npair + p ; k<16 -> dz_A = -R+2p ; k>=16 -> dz_B = dz_A+1 (zero if OOB)
#define FRAGSTRIDE 38400   // u16 per coder (75 frags * 64 lanes * 8)
__global__ __launch_bounds__(64) void k_prep_bfrag(const float* __restrict__ wc1,
                                                   const float* __restrict__ wl1,
                                                   u16* __restrict__ bfrag) {
    int c = blockIdx.x;
    int frag = blockIdx.y;
    int lane = threadIdx.x;
    bool is5 = (c == 1 || c == 2);
    int R = is5 ? 2 : 1;
    int KS = 2 * R + 1;
    int npair = R + 1;
    int nfrag = KS * KS * npair;
    if (frag >= nfrag) return;
    const float* W = is5 ? (wl1 + (size_t)(c - 1) * 32000)
                         : (wc1 + (size_t)((c == 0) ? 0 : (c - 2)) * 6912);
    int dxdy = frag / npair, p = frag - dxdy * npair;
    int dxi = dxdy / KS, dyi = dxdy - dxi * KS;
    int dziA = 2 * p, dziB = 2 * p + 1;
    int co = lane & 15, kg = lane >> 4;
    u16 outv[8];
    #pragma unroll
    for (int j = 0; j < 8; ++j) {
        int k = kg * 8 + j;
        int ci = k & 15;
        int dzi = (k < 16) ? dziA : dziB;
        float v = 0.0f;
        if (dzi < KS)
            v = W[(size_t)((dxi * KS + dyi) * KS + dzi) * 256 + ci * 16 + co];
        outv[j] = (u16)f2bf_rne(v);
    }
    u16* o = bfrag + (size_t)c * FRAGSTRIDE + ((size_t)frag * 64 + lane) * 8;
    uint4 pk;
    pk.x = outv[0] | ((u32)outv[1] << 16);
    pk.y = outv[2] | ((u32)outv[3] << 16);
    pk.z = outv[4] | ((u32)outv[5] << 16);
    pk.w = outv[6] | ((u32)outv[7] << 16);
    *reinterpret_cast<uint4*>(o) = pk;
}

// ---------------------------------------------------------------- conv1 via MFMA 16x16x32 bf16
// WG = 4 waves, each wave owns one output z-line (x, y0+w). LDS stages (4+2R) masked,
// z-padded lines per dx. A-frag: lane reads 16B of voxel (z0+(l&15)+dz) half (l>>4)&1.
// LDS layout: line slot s -> [half][lz] : byte = s*2304 + half*1152 + lz*16 (lz in [0,72))
__global__ __launch_bounds__(256) void k_conv1_mfma(const u16* __restrict__ probf16,
                                                    const u64* __restrict__ lw_in,
                                                    const u16* __restrict__ bfrag,
                                                    const float* __restrict__ bc1,
                                                    const float* __restrict__ bl1,
                                                    u16* __restrict__ hbase,
                                                    int coderBase) {
    int c = coderBase + blockIdx.y;
    bool is5 = (c == 1 || c == 2);
    int R = is5 ? 2 : 1;
    int KS = 2 * R + 1, npair = R + 1;
    const u64* lw = lw_in + (size_t)c * 4096;
    u16* h_c = hbase + (size_t)blockIdx.y * G3 * 16;
    const u16* bf = bfrag + (size_t)c * FRAGSTRIDE;
    const float* bptr = is5 ? (bl1 + (c - 1) * 16)
                            : (bc1 + ((c == 0) ? 0 : (c - 2)) * 16);

    int x = blockIdx.x >> 4;
    int y0 = (blockIdx.x & 15) << 2;
    int w = threadIdx.y;
    int lane = threadIdx.x;
    int yw = y0 + w;

    u64 w0 = rfl64(lw[x * G + yw]);
    u64 anyw = lw[x * G + y0] | lw[x * G + y0 + 1] | lw[x * G + y0 + 2] | lw[x * G + y0 + 3];
    if (anyw == 0ULL) return;          // uniform across WG: safe early-out (no barriers yet)

    __shared__ u32 lds[8 * 2304 / 4];  // 18432 B

    int col = lane & 15, kg = lane >> 4;
    float bv = bptr[col];
    f32x4 acc[4];
    #pragma unroll
    for (int s = 0; s < 4; ++s) acc[s] = (f32x4){bv, bv, bv, bv};

    int nlines = 4 + 2 * R;
    int nunits = nlines * 144;         // 72 lz * 2 halves per line
    int t = w * 64 + lane;

    for (int dx = -R; dx <= R; ++dx) {
        int nx = x + dx;
        __syncthreads();
        if ((unsigned)nx < G) {
            for (int u = t; u < nunits; u += 256) {
                int s = u / 144; int q = u - s * 144;
                int lz = q >> 1, half = q & 1;
                int gz = lz - 4;
                int ny = y0 - R + s;
                uint4 val = make_uint4(0, 0, 0, 0);
                if ((unsigned)ny < G && (unsigned)gz < G) {
                    u64 wn = lw[nx * G + ny];
                    if ((wn >> gz) & 1)
                        val = *reinterpret_cast<const uint4*>(
                            probf16 + ((size_t)((nx * G + ny) * G + gz) * 16 + half * 8));
                }
                *reinterpret_cast<uint4*>(
                    reinterpret_cast<char*>(lds) + s * 2304 + half * 1152 + lz * 16) = val;
            }
        }
        __syncthreads();
        if (w0 == 0ULL || (unsigned)nx >= G) continue;

        for (int dy = -R; dy <= R; ++dy) {
            int ny = yw + dy;
            if ((unsigned)ny >= G) continue;
            u64 wn = rfl64(lw[nx * G + ny]);
            if (wn == 0ULL) continue;
            int slot = w + dy + R;
            for (int p = 0; p < npair; ++p) {
                int dzA = -R + 2 * p;
                int dzB = dzA + 1;
                bool hasB = (dzB <= R);
                u64 hit = tap_hit(w0, wn, dzA);
                if (hasB) hit |= tap_hit(w0, wn, dzB);
                if (hit == 0ULL) continue;
                int frag = ((dx + R) * KS + (dy + R)) * npair + p;
                s16x8 bf8 = *reinterpret_cast<const s16x8*>(bf + ((size_t)frag * 64 + lane) * 8);
                int dz = (kg < 2) ? dzA : (hasB ? dzB : dzA);
                int lzb = (lane & 15) + dz + 4;
                const char* abase = reinterpret_cast<const char*>(lds)
                                    + slot * 2304 + (kg & 1) * 1152;
                #pragma unroll
                for (int s = 0; s < 4; ++s) {
                    if (((hit >> (s * 16)) & 0xFFFFULL) == 0ULL) continue;
                    s16x8 a = *reinterpret_cast<const s16x8*>(abase + (s * 16 + lzb) * 16);
                    acc[s] = __builtin_amdgcn_mfma_f32_16x16x32_bf16(a, bf8, acc[s], 0, 0, 0);
                }
            }
        }
    }

    if (w0 == 0ULL) return;
    u16* hline = h_c + (size_t)(x * G + yw) * G * 16;
    #pragma unroll
    for (int s = 0; s < 4; ++s) {
        #pragma unroll
        for (int r = 0; r < 4; ++r) {
            int z = s * 16 + kg * 4 + r;
            if ((w0 >> z) & 1) {
                float v = fmaxf(acc[s][r], 0.0f);
                hline[z * 16 + col] = (u16)f2bf_rne(v);
            }
        }
    }
}

// ---------------------------------------------------------------- coder conv2 body (C->1, K^3, sigmoid)
template <int KS>
__device__ __forceinline__ void conv2_body(const u32* __restrict__ h_c,
                                           const u64* __restrict__ lwi,
                                           const u64* __restrict__ lwf,
                                           const float* __restrict__ w2,
                                           const float* __restrict__ b2,
                                           float* __restrict__ outp) {
    const int R = KS / 2;
    int z = threadIdx.x;
    int line = blockIdx.x * 4 + threadIdx.y;
    int xx = line >> 6, y = line & 63;
    int v = (xx * G + y) * G + z;
    u64 wf = rfl64(lwf[line]);
    if (wf == 0ULL) { outp[v] = 0.0f; return; }
    bool m = (wf >> z) & 1;

    float acc = b2[0];
    for (int dx = -R; dx <= R; ++dx) {
        int nx = xx + dx; if ((unsigned)nx >= G) continue;
        for (int dy = -R; dy <= R; ++dy) {
            int ny = y + dy; if ((unsigned)ny >= G) continue;
            u64 wn = rfl64(lwi[nx * G + ny]);
            if (wn == 0ULL) continue;
            const float* wbase = w2 + (size_t)(((dx + R) * KS + (dy + R)) * KS) * 16;
            #pragma unroll
            for (int dz = -R; dz <= R; ++dz) {
                if (tap_hit(wf, wn, dz) == 0ULL) continue;
                int nz = z + dz;
                bool ok = (unsigned)nz < G;
                int nzc = ok ? nz : 0;
                bool mn = ok && ((wn >> nzc) & 1);
                const float* w = wbase + (dz + R) * 16;
                if (mn) {
                    const uint4* h4 = reinterpret_cast<const uint4*>(
                        h_c + ((size_t)((nx * G + ny) * G + nzc)) * 8);
                    uint4 Ua = h4[0], Ub = h4[1];
                    u32 uu[8] = {Ua.x, Ua.y, Ua.z, Ua.w, Ub.x, Ub.y, Ub.z, Ub.w};
                    #pragma unroll
                    for (int i = 0; i < 8; ++i) {
                        float lo = __uint_as_float(uu[i] << 16);
                        float hi = __uint_as_float(uu[i] & 0xffff0000u);
                        acc = fmaf(lo, w[2 * i], acc);
                        acc = fmaf(hi, w[2 * i + 1], acc);
                    }
                }
            }
        }
    }
    outp[v] = m ? sigmoidf_(acc) : 0.0f;
}

__global__ __launch_bounds__(256) void k_conv2_all(const u32* __restrict__ hbase,
                                                   const u64* __restrict__ lw_in,
                                                   const u64* __restrict__ lw_fin,
                                                   const float* __restrict__ wc2,
                                                   const float* __restrict__ bc2,
                                                   const float* __restrict__ wl2,
                                                   const float* __restrict__ bl2,
                                                   float* __restrict__ out,
                                                   int coderBase) {
    int c = coderBase + blockIdx.y;
    const u64* lwi = lw_in + (size_t)c * 4096;
    const u64* lwf = lw_fin + (size_t)c * 4096;
    const u32* h_c = hbase + (size_t)blockIdx.y * G3 * 8;
    float* outp = out + (size_t)c * G3;
    if (c == 1 || c == 2) {
        conv2_body<5>(h_c, lwi, lwf, wl2 + (size_t)(c - 1) * 2000, bl2 + (c - 1), outp);
    } else {
        int j = (c == 0) ? 0 : (c - 2);
        conv2_body<3>(h_c, lwi, lwf, wc2 + (size_t)j * 432, bc2 + j, outp);
    }
}

// ---------------------------------------------------------------- launch
extern "C" void kernel_launch(void* const* d_in, const int* in_sizes, int n_in,
                              void* d_out, int out_size, void* d_ws, size_t ws_size,
                              hipStream_t stream) {
    const float* x      = (const float*)d_in[0];
    const float* w_fel1 = (const float*)d_in[3];
    const float* b_fel1 = (const float*)d_in[4];
    const float* w_fel2 = (const float*)d_in[5];
    const float* b_fel2 = (const float*)d_in[6];
    const float* w_up   = (const float*)d_in[7];
    const float* b_up   = (const float*)d_in[8];
    const float* wc1    = (const float*)d_in[9];
    const float* bc1    = (const float*)d_in[10];
    const float* wc2    = (const float*)d_in[11];
    const float* bc2    = (const float*)d_in[12];
    const float* wl1    = (const float*)d_in[13];
    const float* bl1    = (const float*)d_in[14];
    const float* wl2    = (const float*)d_in[15];
    const float* bl2    = (const float*)d_in[16];
    float* out = (float*)d_out;

    char* ws = (char*)d_ws;
    u16*  probf16 = (u16*)(ws);                            // 8 MB  bf16[G3][16]
    float* h1     = (float*)(ws + 8388608);                // 2 MB
    float* h2     = (float*)(ws + 10485760);               // 2 MB
    unsigned char* pocc = (unsigned char*)(ws + 12582912); // 32 KB
    u64* lw_in  = (u64*)(ws + 12615680);                   // 256 KB
    u64* lw_fin = (u64*)(ws + 12877824);                   // 256 KB
    u16* bfrag  = (u16*)(ws + 13139968);                   // 600 KB
    u16* hbase  = (u16*)(ws + 13754368);                   // B * 8 MB (bf16 h)

    const size_t fixed_end = 13754368;
    const size_t hsz = (size_t)G3 * 16 * 2;                // 8 MB per coder
    int B = 2;
    if (fixed_end + 8 * hsz <= ws_size) B = 8;
    else if (fixed_end + 4 * hsz <= ws_size) B = 4;

    k_pocc <<<dim3(S3 / 256), dim3(256), 0, stream>>>(x, pocc);
    k_fel1 <<<dim3(S3 / 256), dim3(256), 0, stream>>>(pocc, w_fel1, b_fel1, h1);
    k_fel2 <<<dim3(S3 / 256), dim3(256), 0, stream>>>(pocc, h1, w_fel2, b_fel2, h2);
    k_up   <<<dim3(S3 / 256), dim3(256), 0, stream>>>(pocc, h2, w_up, b_up, probf16);
    k_masks<<<dim3(16, 64), dim3(64, 4), 0, stream>>>(x, pocc, lw_in, lw_fin, out + (size_t)8 * G3);
    k_prep_bfrag<<<dim3(8, 75), dim3(64), 0, stream>>>(wc1, wl1, bfrag);

    for (int b0 = 0; b0 < 8; b0 += B) {
        int nb = (8 - b0 < B) ? (8 - b0) : B;
        k_conv1_mfma<<<dim3(1024, nb), dim3(64, 4), 0, stream>>>(
            probf16, lw_in, bfrag, bc1, bl1, hbase, b0);
        k_conv2_all<<<dim3(1024, nb), dim3(64, 4), 0, stream>>>(
            (const u32*)hbase, lw_in, lw_fin, wc2, bc2, wl2, bl2, out, b0);
    }
}